// Round 13
// baseline (123.545 us; speedup 1.0000x reference)
//
#include <hip/hip_runtime.h>

typedef long long i64;
typedef unsigned long long u64;
typedef unsigned u32;

// ---------------------------------------------------------------------------
// Established facts (R1-R12):
//  - int64 inputs; int32 output [total*3] neg then [total] keep.
//  - R4 bsearch 53 us; R9 interp ~26 us (bench 123->96.6).
//  - R8 (fewer lines) NEUTRAL, R10 (ILP) NEUTRAL => VALU-inst-count bound:
//    VALUBusy(45%) x 26us == 220 wave-inst/sample x 65536 waves / 1024 SIMDs.
//  - Multi-dispatch + d_ws: 0/4 aborted (R5,R6,R11,R12) vs single-dispatch
//    5/7 passed (R1 proven innocent). Multi-dispatch/ws PERMANENTLY RETIRED.
// This round: delete instructions. Search runs on table entries' HIGH DWORDS
// (keys < 2^59; hi-dword = h<<10 | r>>11, ~27 significant bits, dup prob
// ~2e-4): u32 compares + float-carried endpoints => ~19 inst/iter vs ~35.
// Final <=8-entry window verified with full u64 compares. Corruption math in
// 32-bit (ids < 2^21), low-dword loads of pos/rand. ~145 inst/sample vs 220.
// ---------------------------------------------------------------------------

__global__ __launch_bounds__(256) void neg_sample_fast(
    const void* __restrict__ pos, const void* __restrict__ rand_vals,
    const void* __restrict__ table_v,
    int* __restrict__ out_neg, int* __restrict__ out_keep,
    int total, int split, int L, unsigned num_negs)
{
    unsigned i = blockIdx.x * blockDim.x + threadIdx.x;
    if (i >= (unsigned)total) return;

    // Width probe (R2-proven): pos int32-view word 3 == 0 iff int64 storage.
    const int* pw = (const int*)pos;
    if (pw[3] == 0) {
        // ------------------- int64 fast path (the real path) -------------------
        const int* pos32  = (const int*)pos;       // low dwords of int64 (LE)
        const int* rand32 = (const int*)rand_vals;
        const i64* table  = (const i64*)table_v;
        const u32* t32    = (const u32*)table_v;   // t32[2j+1] = hi dword of entry j

        unsigned b = i / num_negs;                 // num_negs=64 -> shift
        int h = pos32[6 * b + 0];
        int r = pos32[6 * b + 2];
        int t = pos32[6 * b + 4];
        int rv = rand32[2 * i];

        const bool ch = (i < (unsigned)split);
        int orig = ch ? h : t;
        // pad_idx==0 fast path: rng in [1, NUM_ENTITIES); shift past original
        int repl = rv + (((rv >= orig) & (orig > 0)) ? 1 : 0);
        if (ch) h = repl; else t = repl;

        u64 key = ((u64)(u32)h << 42) | ((u64)(u32)r << 21) | (u64)(u32)t;
        u32 khi = ((u32)h << 10) | ((u32)r >> 11);   // key bits 32..63, exact

        u32 v0 = t32[1];
        u32 vN = t32[2 * (L - 1) + 1];
        bool in_set = false;
        if (khi >= v0 && khi <= vN) {
            // interp search on hi-dwords, float endpoints carried across iters.
            int lo = 0, hi = L - 1;
            float flo = (float)v0, fhi = (float)vN, fk = (float)khi;
            while (hi - lo > 8) {
                float denom = fhi - flo;
                if (denom < 1.0f) denom = 1.0f;          // dup guard, no div0
                float f = (fk - flo) * __builtin_amdgcn_rcpf(denom);
                int mid = lo + (int)(f * (float)(hi - lo));
                if (mid <= lo) mid = lo + 1;             // strict interior =>
                if (mid >= hi) mid = hi - 1;             // window shrinks >=1
                u32 v = t32[2 * mid + 1];
                if (v < khi) { lo = mid; flo = (float)v; }
                else         { hi = mid; fhi = (float)v; }
            }
            // verify window: full u64 compares; exit at first hi-dword > khi.
            for (int j = lo; j < L; ++j) {
                u64 v = (u64)table[j];
                if ((u32)(v >> 32) > khi) break;
                in_set |= (v == key);
            }
        }

        out_neg[3 * (size_t)i + 0] = h;
        out_neg[3 * (size_t)i + 1] = r;
        out_neg[3 * (size_t)i + 2] = t;
        out_keep[i] = in_set ? 0 : 1;
    } else {
        // ---------------- int32-storage fallback (never yet taken) ----------------
        const int* posi  = (const int*)pos;
        const int* randi = (const int*)rand_vals;
        const int* tabi  = (const int*)table_v;

        unsigned b = i / num_negs;
        i64 h = (i64)posi[3 * b + 0];
        i64 r = (i64)posi[3 * b + 1];
        i64 t = (i64)posi[3 * b + 2];
        i64 rv = (i64)randi[i];
        const bool ch = (i < (unsigned)split);
        i64 orig = ch ? h : t;
        i64 repl = rv + (((rv >= orig) & (orig > 0)) ? 1 : 0);
        if (ch) h = repl; else t = repl;
        u64 key = ((u64)h << 42) | ((u64)r << 21) | (u64)t;

        int low = 0, size = L;
        while (size > 0) {
            int half = size >> 1;
            int mid = low + half;
            u64 v = (u64)(i64)tabi[mid];
            if (v < key) { low = mid + 1; size -= half + 1; }
            else         { size = half; }
        }
        bool in_set = (low < L) && ((u64)(i64)tabi[low] == key);

        out_neg[3 * (size_t)i + 0] = (int)h;
        out_neg[3 * (size_t)i + 1] = (int)r;
        out_neg[3 * (size_t)i + 2] = (int)t;
        out_keep[i] = in_set ? 0 : 1;
    }
}

extern "C" void kernel_launch(void* const* d_in, const int* in_sizes, int n_in,
                              void* d_out, int out_size, void* d_ws, size_t ws_size,
                              hipStream_t stream) {
    const void* pos       = d_in[0];
    const void* rand_vals = d_in[1];
    const void* table     = d_in[2];

    const int B     = in_sizes[0] / 3;
    const int total = in_sizes[1];
    const int L     = in_sizes[2];
    const unsigned num_negs = (unsigned)(total / B);
    const int split = (total + 1) / 2;   // ceil(total/2)

    int* out_neg  = (int*)d_out;
    int* out_keep = out_neg + (size_t)total * 3;

    const int threads = 256;
    const int blocks  = (total + threads - 1) / threads;
    neg_sample_fast<<<blocks, threads, 0, stream>>>(
        pos, rand_vals, table, out_neg, out_keep, total, split, L, num_negs);
}

// Round 14
// 121.934 us; speedup vs baseline: 1.0132x; 1.0132x over previous
//
#include <hip/hip_runtime.h>

typedef long long i64;
typedef unsigned long long u64;
typedef unsigned u32;

// ---------------------------------------------------------------------------
// Established facts (R1-R13):
//  - int64 inputs; int32 output [total*3] neg then [total] keep.
//  - Single dispatch, no d_ws/atomics/cross-lane: 6/8 passed; multi-dispatch
//    + d_ws: 0/4 aborted => PERMANENTLY RETIRED.
//  - R4 bsearch 53 us; R9 full-key interp ~26 us; R13 hi-dword interp 53 us.
//  - R13 ROOT CAUSE: r < 2^11 => hi dword == h<<10 exactly (no r bits!) ->
//    ~10-entry equal-value runs -> denom-clamp crawl (1 entry/iter) + ~18-max
//    divergent verify scan. NEVER search a non-unique projection.
//  - Cost model: wave-MAX trip counts dominate (divergent variable loops);
//    R8 (line traffic) and R10 (MLP) nulls rule out BW/latency as binding.
// This round: full-key interp (unique keys -> no crawl; strict-interior mid
// clamp -> guaranteed shrink, provable termination) + cheap float mids via
// exact split key = (h<<10)*2^32 + (r<<21|t) (one fma per value) + BRANCHLESS
// fixed 8-wide verify (idx = min(lo+k, hi): in-bounds, idempotent, no breaks).
// ---------------------------------------------------------------------------

__device__ __forceinline__ float fkey_of(u64 v) {
    // exact dword split -> float; ULP(2^58)=2^35 error is harmless: mids are
    // heuristics only, lo/hi updates use exact u64 compares.
    return __builtin_fmaf((float)(u32)(v >> 32), 4294967296.0f, (float)(u32)v);
}

__global__ __launch_bounds__(256) void neg_sample_fast(
    const void* __restrict__ pos, const void* __restrict__ rand_vals,
    const void* __restrict__ table_v,
    int* __restrict__ out_neg, int* __restrict__ out_keep,
    int total, int split, int L, unsigned num_negs)
{
    unsigned i = blockIdx.x * blockDim.x + threadIdx.x;
    if (i >= (unsigned)total) return;

    // Width probe (R2-proven): pos int32-view word 3 == 0 iff int64 storage.
    const int* pw = (const int*)pos;
    if (pw[3] == 0) {
        // ---------------- int64 fast path (the real path) ----------------
        const int* pos32  = (const int*)pos;       // low dwords of int64 (LE)
        const int* rand32 = (const int*)rand_vals;
        const i64* table  = (const i64*)table_v;

        unsigned b = i / num_negs;                 // num_negs=64 -> shift
        int h = pos32[6 * b + 0];
        int r = pos32[6 * b + 2];
        int t = pos32[6 * b + 4];
        int rv = rand32[2 * i];

        const bool ch = (i < (unsigned)split);
        int orig = ch ? h : t;
        // pad_idx==0 fast path: rng in [1, NUM_ENTITIES); shift past original
        int repl = rv + (((rv >= orig) & (orig > 0)) ? 1 : 0);
        if (ch) h = repl; else t = repl;

        // exact 32/32 split of key = h<<42 | r<<21 | t
        u32 khi = ((u32)h << 10) | ((u32)r >> 11);
        u32 klo = ((u32)r << 21) | (u32)t;
        u64 key = ((u64)khi << 32) | (u64)klo;

        u64 v0 = (u64)table[0];                    // wave-uniform, L1-hot
        u64 vN = (u64)table[L - 1];

        bool in_set;
        if (key <= v0)      in_set = (key == v0);
        else if (key >= vN) in_set = (key == vN);
        else {
            // invariant: table[lo] < key < ... <= table[hi], exact compares.
            int lo = 0, hi = L - 1;
            float flo = fkey_of(v0), fhi = fkey_of(vN);
            const float fk = __builtin_fmaf((float)khi, 4294967296.0f,
                                            (float)klo);
            while (hi - lo > 8) {
                float denom = fmaxf(fhi - flo, 1.0f);
                float f = (fk - flo) * __builtin_amdgcn_rcpf(denom);
                f = fminf(fmaxf(f, 0.0f), 1.0f);
                int mid = lo + (int)(f * (float)(hi - lo));
                if (mid <= lo) mid = lo + 1;       // strict interior =>
                if (mid >= hi) mid = hi - 1;       // window shrinks >= 1
                u64 v = (u64)table[mid];
                float fv = fkey_of(v);
                if (v < key) { lo = mid; flo = fv; }
                else         { hi = mid; fhi = fv; }
            }
            // branchless fixed verify of (lo, hi]: clamp makes loads in-bounds
            // and duplicate compares idempotent (table[hi] may repeat).
            bool eq = false;
#pragma unroll
            for (int k = 1; k <= 8; ++k) {
                int idx = lo + k;
                idx = idx > hi ? hi : idx;
                eq |= ((u64)table[idx] == key);    // 8 independent loads
            }
            in_set = eq;
        }

        out_neg[3 * (size_t)i + 0] = h;
        out_neg[3 * (size_t)i + 1] = r;
        out_neg[3 * (size_t)i + 2] = t;
        out_keep[i] = in_set ? 0 : 1;
    } else {
        // ---------- int32-storage fallback (never yet taken; insurance) ----------
        const int* posi  = (const int*)pos;
        const int* randi = (const int*)rand_vals;
        const int* tabi  = (const int*)table_v;

        unsigned b = i / num_negs;
        i64 h = (i64)posi[3 * b + 0];
        i64 r = (i64)posi[3 * b + 1];
        i64 t = (i64)posi[3 * b + 2];
        i64 rv = (i64)randi[i];
        const bool ch = (i < (unsigned)split);
        i64 orig = ch ? h : t;
        i64 repl = rv + (((rv >= orig) & (orig > 0)) ? 1 : 0);
        if (ch) h = repl; else t = repl;
        u64 key = ((u64)h << 42) | ((u64)r << 21) | (u64)t;

        int low = 0, size = L;
        while (size > 0) {
            int half = size >> 1;
            int mid = low + half;
            u64 v = (u64)(i64)tabi[mid];
            if (v < key) { low = mid + 1; size -= half + 1; }
            else         { size = half; }
        }
        bool in_set = (low < L) && ((u64)(i64)tabi[low] == key);

        out_neg[3 * (size_t)i + 0] = (int)h;
        out_neg[3 * (size_t)i + 1] = (int)r;
        out_neg[3 * (size_t)i + 2] = (int)t;
        out_keep[i] = in_set ? 0 : 1;
    }
}

extern "C" void kernel_launch(void* const* d_in, const int* in_sizes, int n_in,
                              void* d_out, int out_size, void* d_ws, size_t ws_size,
                              hipStream_t stream) {
    const void* pos       = d_in[0];
    const void* rand_vals = d_in[1];
    const void* table     = d_in[2];

    const int B     = in_sizes[0] / 3;
    const int total = in_sizes[1];
    const int L     = in_sizes[2];
    const unsigned num_negs = (unsigned)(total / B);
    const int split = (total + 1) / 2;   // ceil(total/2)

    int* out_neg  = (int*)d_out;
    int* out_keep = out_neg + (size_t)total * 3;

    const int threads = 256;
    const int blocks  = (total + threads - 1) / threads;
    neg_sample_fast<<<blocks, threads, 0, stream>>>(
        pos, rand_vals, table, out_neg, out_keep, total, split, L, num_negs);
}